// Round 7
// baseline (123.468 us; speedup 1.0000x reference)
//
#include <hip/hip_runtime.h>
#include <hip/hip_bf16.h>

#define B_   2
#define N_   2048
#define CIN  256
#define NH   8
#define CH   32

typedef unsigned short u16;
typedef __attribute__((ext_vector_type(4))) float f32x4;
typedef __bf16 bf16x8 __attribute__((ext_vector_type(8)));
typedef u16 u16x4 __attribute__((ext_vector_type(4)));
typedef u16 u16x8 __attribute__((ext_vector_type(8)));

static __device__ __forceinline__ u16 b16(float f) {
    __bf16 h = (__bf16)f;
    union { __bf16 h; u16 u; } c; c.h = h; return c.u;
}
static __device__ __forceinline__ float bf2f(u16 u) {
    union { unsigned u; float f; } c; c.u = ((unsigned)u) << 16; return c.f;
}
static __device__ __forceinline__ float sigmoidf_(float x) {
    return 1.0f / (1.0f + __expf(-x));
}

// ---------------------------------------------------------------------------
// 4 dispatches:
//  D1 prep80 : transpose+convert the 5 weight matrices once (80 blocks).
//  D2 proj   : staged 64x64 MFMA projections; X staged straight from f32.
//  D3 attn   : flash attention, key-split 2x, bias loaded DIRECTLY into the
//              MFMA C-operand registers (depth-4 ring, 3 tiles ahead; K/V
//              ping-pong 2 ahead). No bias LDS, no DMA, no manual vmcnt --
//              compiler emits precise counted waits on register deps.
//  D4 out    : staged 64x64 MFMA output projection.
// ---------------------------------------------------------------------------
#define LDW 136   // padded LDS row (u16): 272B; 272%128=16B -> conflict-free b128

static __device__ __forceinline__ u16x8 cvt8(float4 a, float4 b) {
    u16x8 o;
    o[0] = b16(a.x); o[1] = b16(a.y); o[2] = b16(a.z); o[3] = b16(a.w);
    o[4] = b16(b.x); o[5] = b16(b.y); o[6] = b16(b.z); o[7] = b16(b.w);
    return o;
}
static __device__ __forceinline__ void stg_b16(const u16* __restrict__ src, u16 (*dst)[LDW], int tid) {
#pragma unroll
    for (int i = 0; i < 4; i++) {
        const int e = tid + 256 * i, row = e >> 4, c = e & 15;
        *(bf16x8*)&dst[row][c * 8] = *(const bf16x8*)(src + (size_t)row * CIN + c * 8);
    }
}
static __device__ __forceinline__ void ld1_b16(const u16* __restrict__ src, bf16x8 r[4], int tid) {
#pragma unroll
    for (int i = 0; i < 4; i++) {
        const int e = tid + 256 * i, row = e >> 4, c = e & 15;
        r[i] = *(const bf16x8*)(src + (size_t)row * CIN + 128 + c * 8);
    }
}
static __device__ __forceinline__ void wr1_b16(const bf16x8 r[4], u16 (*dst)[LDW], int tid) {
#pragma unroll
    for (int i = 0; i < 4; i++) {
        const int e = tid + 256 * i, row = e >> 4, c = e & 15;
        *(bf16x8*)&dst[row][c * 8] = r[i];
    }
}
static __device__ __forceinline__ void stg_f32(const float* __restrict__ src, u16 (*dst)[LDW], int tid) {
#pragma unroll
    for (int i = 0; i < 4; i++) {
        const int e = tid + 256 * i, row = e >> 4, c = e & 15;
        const float* s = src + (size_t)row * CIN + c * 8;
        *(u16x8*)&dst[row][c * 8] = cvt8(*(const float4*)s, *(const float4*)(s + 4));
    }
}
static __device__ __forceinline__ void compute_phase(
    const u16 (*At)[LDW], const u16 (*Bt)[LDW], int w, int lr, int lq, f32x4 acc[4])
{
#pragma unroll
    for (int kk = 0; kk < 128; kk += 32) {
        bf16x8 af = *(const bf16x8*)&At[w * 16 + lr][kk + lq * 8];
#pragma unroll
        for (int nt = 0; nt < 4; nt++) {
            bf16x8 bf = *(const bf16x8*)&Bt[nt * 16 + lr][kk + lq * 8];
            acc[nt] = __builtin_amdgcn_mfma_f32_16x16x32_bf16(af, bf, acc[nt], 0, 0, 0);
        }
    }
}

// ---------------------------------------------------------------------------
// D1: 80 blocks -- transpose+convert weights -> Wt[n][k] bf16 (scale on Wq)
// ---------------------------------------------------------------------------
__global__ __launch_bounds__(256)
void prep80(const float* __restrict__ Wq, const float* __restrict__ Wk,
            const float* __restrict__ Wv, const float* __restrict__ Wg,
            const float* __restrict__ Wo,
            u16* __restrict__ WqT, u16* __restrict__ WkT,
            u16* __restrict__ WvT, u16* __restrict__ WgT,
            u16* __restrict__ WoT)
{
    const int wz = blockIdx.x;
    const int tid = threadIdx.x;
    const int z = wz >> 4, t16 = wz & 15;
    const int k0 = (t16 & 3) * 64, n0 = (t16 >> 2) * 64;
    const float* W = (z == 0) ? Wq : (z == 1) ? Wk : (z == 2) ? Wv : (z == 3) ? Wg : Wo;
    u16* Wt = (z == 0) ? WqT : (z == 1) ? WkT : (z == 2) ? WvT : (z == 3) ? WgT : WoT;
    const float s = (z == 0) ? 0.17677669529663687f : 1.0f;

    __shared__ float T[64][65];
    const int a = tid >> 4, c4 = (tid & 15) * 4;
#pragma unroll
    for (int i = 0; i < 4; i++) {
        float4 v = *(const float4*)&W[(size_t)(k0 + a + i * 16) * CIN + n0 + c4];
        T[a + i * 16][c4 + 0] = v.x * s; T[a + i * 16][c4 + 1] = v.y * s;
        T[a + i * 16][c4 + 2] = v.z * s; T[a + i * 16][c4 + 3] = v.w * s;
    }
    __syncthreads();
#pragma unroll
    for (int i = 0; i < 4; i++) {
        const int nr = a + i * 16;
        u16x4 o;
        o[0] = b16(T[c4 + 0][nr]); o[1] = b16(T[c4 + 1][nr]);
        o[2] = b16(T[c4 + 2][nr]); o[3] = b16(T[c4 + 3][nr]);
        *(u16x4*)&Wt[(size_t)(n0 + nr) * CIN + k0 + c4] = o;
    }
}

// ---------------------------------------------------------------------------
// D2: projections (z=0 Q, z=1 K, z=2 Vt, z=3 G); X staged from f32 (r4-valid)
// ---------------------------------------------------------------------------
__global__ __launch_bounds__(256, 4)
void proj_mfma(const float* __restrict__ qx, const float* __restrict__ kvx,
               const u16* __restrict__ WqT, const u16* __restrict__ WkT,
               const u16* __restrict__ WvT, const u16* __restrict__ WgT,
               const float* __restrict__ bgv,
               u16* __restrict__ Qw, u16* __restrict__ Kw,
               u16* __restrict__ Vt, u16* __restrict__ Gw)
{
    const int z = blockIdx.z;
    const int tid = threadIdx.x, w = tid >> 6, l = tid & 63, lr = l & 15, lq = l >> 4;

    __shared__ u16 At[64][LDW];
    __shared__ u16 Bt[64][LDW];

    f32x4 acc[4] = {{0,0,0,0},{0,0,0,0},{0,0,0,0},{0,0,0,0}};

    if (z != 2) {
        const float* Af = ((z == 1) ? kvx : qx) + (size_t)(blockIdx.y * 64) * CIN;
        const u16*   Bb = ((z == 0) ? WqT : (z == 1) ? WkT : WgT) + (size_t)(blockIdx.x * 64) * CIN;
        stg_f32(Af, At, tid);
        stg_b16(Bb, Bt, tid);
        __syncthreads();
        float4 raf[8]; bf16x8 rb[4];
#pragma unroll
        for (int i = 0; i < 4; i++) {
            const int e = tid + 256 * i, row = e >> 4, c = e & 15;
            const float* s = Af + (size_t)row * CIN + 128 + c * 8;
            raf[2 * i] = *(const float4*)s; raf[2 * i + 1] = *(const float4*)(s + 4);
        }
        ld1_b16(Bb, rb, tid);
        compute_phase(At, Bt, w, lr, lq, acc);
        __syncthreads();
#pragma unroll
        for (int i = 0; i < 4; i++) {
            const int e = tid + 256 * i, row = e >> 4, c = e & 15;
            *(u16x8*)&At[row][c * 8] = cvt8(raf[2 * i], raf[2 * i + 1]);
        }
        wr1_b16(rb, Bt, tid);
        __syncthreads();
        compute_phase(At, Bt, w, lr, lq, acc);

        const int m0 = blockIdx.y * 64 + w * 16, n0 = blockIdx.x * 64;
        if (z == 3) {
#pragma unroll
            for (int nt = 0; nt < 4; nt++) {
                const int col = n0 + nt * 16 + lr;
                const float bb = bgv[col];
#pragma unroll
                for (int r = 0; r < 4; r++)
                    Gw[(size_t)(m0 + lq * 4 + r) * CIN + col] = b16(sigmoidf_(acc[nt][r] + bb));
            }
        } else {
            u16* D = (z == 0) ? Qw : Kw;
#pragma unroll
            for (int nt = 0; nt < 4; nt++)
#pragma unroll
                for (int r = 0; r < 4; r++)
                    D[(size_t)(m0 + lq * 4 + r) * CIN + n0 + nt * 16 + lr] = b16(acc[nt][r]);
        }
    } else {
        const u16*   Ab = WvT + (size_t)(blockIdx.x * 64) * CIN;
        const float* Bf = kvx + (size_t)(blockIdx.y * 64) * CIN;
        stg_b16(Ab, At, tid);
        stg_f32(Bf, Bt, tid);
        __syncthreads();
        bf16x8 ra[4]; float4 rbf[8];
        ld1_b16(Ab, ra, tid);
#pragma unroll
        for (int i = 0; i < 4; i++) {
            const int e = tid + 256 * i, row = e >> 4, c = e & 15;
            const float* s = Bf + (size_t)row * CIN + 128 + c * 8;
            rbf[2 * i] = *(const float4*)s; rbf[2 * i + 1] = *(const float4*)(s + 4);
        }
        compute_phase(At, Bt, w, lr, lq, acc);
        __syncthreads();
        wr1_b16(ra, At, tid);
#pragma unroll
        for (int i = 0; i < 4; i++) {
            const int e = tid + 256 * i, row = e >> 4, c = e & 15;
            *(u16x8*)&Bt[row][c * 8] = cvt8(rbf[2 * i], rbf[2 * i + 1]);
        }
        __syncthreads();
        compute_phase(At, Bt, w, lr, lq, acc);

        const int c0 = blockIdx.x * 64 + w * 16;
        const int n0g = blockIdx.y * 64;
        const int bb_ = n0g >> 11, nl0 = n0g & (N_ - 1);
#pragma unroll
        for (int nt = 0; nt < 4; nt++)
#pragma unroll
            for (int r = 0; r < 4; r++)
                Vt[((size_t)bb_ * CIN + c0 + lq * 4 + r) * N_ + nl0 + nt * 16 + lr] = b16(acc[nt][r]);
    }
}

// ---------------------------------------------------------------------------
// D3: flash attention, key-split 2x, REGISTER-RING bias (no LDS, no DMA).
// Block = (b, h, 32 q-rows): wave w -> q-half rp=w&1, key-half kh=w>>1 (32
// tiles of 32 keys). Bias C-operand loaded directly into registers, ring
// depth 4, issued 3 tiles ahead; K/V ping-pong registers issued 2 ahead.
// Compiler emits precise counted vmcnt waits from register deps; t-loop
// unrolled x4 so all ring indices are static (no scratch).
// ---------------------------------------------------------------------------
#define RMAX(x) { x = fmaxf(x, __shfl_xor(x, 1)); x = fmaxf(x, __shfl_xor(x, 2)); \
                  x = fmaxf(x, __shfl_xor(x, 4)); x = fmaxf(x, __shfl_xor(x, 8)); }
#define RSUM(x) { x += __shfl_xor(x, 1); x += __shfl_xor(x, 2); \
                  x += __shfl_xor(x, 4); x += __shfl_xor(x, 8); }

__global__ __launch_bounds__(256)
void attn_kernel(const u16* __restrict__ Qw, const u16* __restrict__ Kw,
                 const u16* __restrict__ Vt, const float* __restrict__ bias,
                 const u16* __restrict__ Gw, u16* __restrict__ Owg)
{
    const int bid = blockIdx.x;
    const int h = bid & 7, qt = (bid >> 3) & 63, b = bid >> 9;
    const int tid = threadIdx.x;
    const int w = tid >> 6, l = tid & 63, lr = l & 15, lq = l >> 4;
    const int rp = w & 1, kh = w >> 1;
    const int qb = qt * 32;

    __shared__ float Mrg[2][544];          // key-half merge buffer (4.25 KB)
    __shared__ u16 Plds[4][8][4][16];      // wave-private P staging (4 KB)

    const bf16x8 qf = *(const bf16x8*)(Qw + (size_t)(b * N_ + qb + rp * 16 + lr) * CIN + h * CH + lq * 8);
    const u16* Kb = Kw + (size_t)(b * N_ + kh * 1024 + lr) * CIN + h * CH + lq * 8;
    const u16* Vb = Vt + (size_t)((b * NH + h) * CH + lr) * N_ + kh * 1024 + lq * 8;
    const float* bW = bias + ((size_t)(b * NH + h) * N_ + qb + rp * 16) * N_ + kh * 1024;
    // per-lane row pointers for direct C-operand loads (row = lq*4+r, col = lr)
    const float* bR0 = bW + (size_t)(lq * 4) * N_ + lr;
    const float* bR1 = bR0 + N_;
    const float* bR2 = bR1 + N_;
    const float* bR3 = bR2 + N_;

#define BLOAD(T, BA, BB) { \
    const int co_ = (T) * 32; \
    BA[0] = bR0[co_];      BA[1] = bR1[co_];      BA[2] = bR2[co_];      BA[3] = bR3[co_]; \
    BB[0] = bR0[co_ + 16]; BB[1] = bR1[co_ + 16]; BB[2] = bR2[co_ + 16]; BB[3] = bR3[co_ + 16]; }

#define KVLOAD(K, K0, K1, V0, V1) { \
    K0 = *(const bf16x8*)(Kb + (size_t)(K) * CIN); \
    K1 = *(const bf16x8*)(Kb + (size_t)((K) + 16) * CIN); \
    V0 = *(const bf16x8*)(Vb + (K)); \
    V1 = *(const bf16x8*)(Vb + 16 * N_ + (K)); }

    f32x4 acc0 = {0.f, 0.f, 0.f, 0.f}, acc1 = {0.f, 0.f, 0.f, 0.f};
    float m0v = 8.f, m1v = 8.f, m2v = 8.f, m3v = 8.f;   // defer-max init
    float l0 = 0.f, l1 = 0.f, l2 = 0.f, l3 = 0.f;
    f32x4 bA0, bB0, bA1, bB1, bA2, bB2, bA3, bB3;        // bias ring (static idx)
    bf16x8 ka0, ka1, va0, va1, kb0, kb1, vb0, vb1;       // K/V ping-pong

    BLOAD(0, bA0, bB0)
    KVLOAD(0, ka0, ka1, va0, va1)
    BLOAD(1, bA1, bB1)
    KVLOAD(32, kb0, kb1, vb0, vb1)
    BLOAD(2, bA2, bB2)
    __builtin_amdgcn_sched_barrier(0);

#define TBODY(t, BA, BB, NBA, NBB, K0, K1, V0, V1) { \
    const bf16x8 ck0 = K0, ck1 = K1, cv0 = V0, cv1 = V1; \
    f32x4 c0, c1; \
    c0[0] = BA[0]; c0[1] = BA[1]; c0[2] = BA[2]; c0[3] = BA[3]; \
    c1[0] = BB[0]; c1[1] = BB[1]; c1[2] = BB[2]; c1[3] = BB[3]; \
    KVLOAD((((t) + 2) & 31) * 32, K0, K1, V0, V1) \
    BLOAD(((t) + 3) & 31, NBA, NBB) \
    __builtin_amdgcn_sched_barrier(0); \
    f32x4 s0 = __builtin_amdgcn_mfma_f32_16x16x32_bf16(qf, ck0, c0, 0, 0, 0); \
    f32x4 s1 = __builtin_amdgcn_mfma_f32_16x16x32_bf16(qf, ck1, c1, 0, 0, 0); \
    float pm0 = fmaxf(s0[0], s1[0]); \
    float pm1 = fmaxf(s0[1], s1[1]); \
    float pm2 = fmaxf(s0[2], s1[2]); \
    float pm3 = fmaxf(s0[3], s1[3]); \
    bool ev = (pm0 > m0v) || (pm1 > m1v) || (pm2 > m2v) || (pm3 > m3v); \
    if (__any(ev)) { \
        RMAX(pm0) RMAX(pm1) RMAX(pm2) RMAX(pm3) \
        float t0 = fmaxf(m0v, pm0), t1 = fmaxf(m1v, pm1); \
        float t2 = fmaxf(m2v, pm2), t3 = fmaxf(m3v, pm3); \
        float sc0 = __expf(m0v - t0), sc1 = __expf(m1v - t1); \
        float sc2 = __expf(m2v - t2), sc3 = __expf(m3v - t3); \
        m0v = t0; m1v = t1; m2v = t2; m3v = t3; \
        l0 *= sc0; l1 *= sc1; l2 *= sc2; l3 *= sc3; \
        acc0[0] *= sc0; acc0[1] *= sc1; acc0[2] *= sc2; acc0[3] *= sc3; \
        acc1[0] *= sc0; acc1[1] *= sc1; acc1[2] *= sc2; acc1[3] *= sc3; \
    } \
    float p00 = __expf(s0[0] - m0v), p01 = __expf(s0[1] - m1v); \
    float p02 = __expf(s0[2] - m2v), p03 = __expf(s0[3] - m3v); \
    float p10 = __expf(s1[0] - m0v), p11 = __expf(s1[1] - m1v); \
    float p12 = __expf(s1[2] - m2v), p13 = __expf(s1[3] - m3v); \
    l0 += p00 + p10; l1 += p01 + p11; l2 += p02 + p12; l3 += p03 + p13; \
    u16* pw = &Plds[w][0][lq][lr]; \
    pw[0 * 64] = b16(p00); pw[1 * 64] = b16(p01); \
    pw[2 * 64] = b16(p02); pw[3 * 64] = b16(p03); \
    pw[4 * 64] = b16(p10); pw[5 * 64] = b16(p11); \
    pw[6 * 64] = b16(p12); pw[7 * 64] = b16(p13); \
    const bf16x8 pa = *(const bf16x8*)&Plds[w][(lq >> 1) * 4 + (lr & 3)][lr >> 2][(lq & 1) * 8]; \
    acc0 = __builtin_amdgcn_mfma_f32_16x16x32_bf16(pa, cv0, acc0, 0, 0, 0); \
    acc1 = __builtin_amdgcn_mfma_f32_16x16x32_bf16(pa, cv1, acc1, 0, 0, 0); }

    for (int tt = 0; tt < 8; ++tt) {
        TBODY(tt * 4 + 0, bA0, bB0, bA3, bB3, ka0, ka1, va0, va1)
        TBODY(tt * 4 + 1, bA1, bB1, bA0, bB0, kb0, kb1, vb0, vb1)
        TBODY(tt * 4 + 2, bA2, bB2, bA1, bB1, ka0, ka1, va0, va1)
        TBODY(tt * 4 + 3, bA3, bB3, bA2, bB2, kb0, kb1, vb0, vb1)
    }
#undef TBODY
#undef BLOAD
#undef KVLOAD

    RSUM(l0) RSUM(l1) RSUM(l2) RSUM(l3)

    // ---- in-LDS merge of the two key-halves ----
    float* P = Mrg[rp];
    if (kh == 1) {                          // waves 2,3 publish partials
#pragma unroll
        for (int r = 0; r < 4; r++) {
            const int row = lq * 4 + r;
            P[row * 32 + lr]      = acc0[r];
            P[row * 32 + 16 + lr] = acc1[r];
        }
        if (lr == 0) {
            P[512 + lq * 4 + 0] = m0v; P[512 + lq * 4 + 1] = m1v;
            P[512 + lq * 4 + 2] = m2v; P[512 + lq * 4 + 3] = m3v;
            P[528 + lq * 4 + 0] = l0;  P[528 + lq * 4 + 1] = l1;
            P[528 + lq * 4 + 2] = l2;  P[528 + lq * 4 + 3] = l3;
        }
    }
    __syncthreads();
    if (kh == 1) return;

    const float mA[4] = {m0v, m1v, m2v, m3v};
    const float lA[4] = {l0, l1, l2, l3};

    const u16* Gb = Gw + (size_t)(b * N_ + qb + rp * 16 + lq * 4) * CIN + h * CH + lr;
    u16* Ob = Owg + (size_t)(b * N_ + qb + rp * 16 + lq * 4) * CIN + h * CH + lr;
#pragma unroll
    for (int r = 0; r < 4; r++) {
        const int row = lq * 4 + r;
        const float mB = P[512 + row];
        const float lB = P[528 + row];
        const float ob0 = P[row * 32 + lr];
        const float ob1 = P[row * 32 + 16 + lr];
        const float mM = fmaxf(mA[r], mB);
        const float sA = __expf(mA[r] - mM), sB = __expf(mB - mM);
        const float rr = 1.0f / (lA[r] * sA + lB * sB);
        const float a0 = (r == 0 ? acc0[0] : r == 1 ? acc0[1] : r == 2 ? acc0[2] : acc0[3]);
        const float a1 = (r == 0 ? acc1[0] : r == 1 ? acc1[1] : r == 2 ? acc1[2] : acc1[3]);
        const float g0 = bf2f(Gb[r * CIN]), g1 = bf2f(Gb[r * CIN + 16]);
        Ob[r * CIN]      = b16((a0 * sA + ob0 * sB) * rr * g0);
        Ob[r * CIN + 16] = b16((a1 * sA + ob1 * sB) * rr * g1);
    }
}

// ---------------------------------------------------------------------------
// D4: out = Owg @ Wo + bo  (staged 64x64 core, round-3 validated)
// ---------------------------------------------------------------------------
__global__ __launch_bounds__(256, 4)
void out_mfma(const u16* __restrict__ Owg, const u16* __restrict__ WoT,
              const float* __restrict__ bo, float* __restrict__ out)
{
    const int tid = threadIdx.x, w = tid >> 6, l = tid & 63, lr = l & 15, lq = l >> 4;
    const int m0 = blockIdx.y * 64 + w * 16, n0 = blockIdx.x * 64;

    __shared__ u16 At[64][LDW];
    __shared__ u16 Bt[64][LDW];

    const u16* Arows = Owg + (size_t)(blockIdx.y * 64) * CIN;
    const u16* Brows = WoT + (size_t)(blockIdx.x * 64) * CIN;

    f32x4 acc[4] = {{0,0,0,0},{0,0,0,0},{0,0,0,0},{0,0,0,0}};

    stg_b16(Arows, At, tid);
    stg_b16(Brows, Bt, tid);
    __syncthreads();
    bf16x8 ra[4], rb[4];
    ld1_b16(Arows, ra, tid);
    ld1_b16(Brows, rb, tid);
    compute_phase(At, Bt, w, lr, lq, acc);
    __syncthreads();
    wr1_b16(ra, At, tid);
    wr1_b16(rb, Bt, tid);
    __syncthreads();
    compute_phase(At, Bt, w, lr, lq, acc);

#pragma unroll
    for (int nt = 0; nt < 4; nt++) {
        const float bb = bo[n0 + nt * 16 + lr];
#pragma unroll
        for (int r = 0; r < 4; r++)
            out[(size_t)(m0 + lq * 4 + r) * CIN + n0 + nt * 16 + lr] = acc[nt][r] + bb;
    }
}

// ---------------------------------------------------------------------------
extern "C" void kernel_launch(void* const* d_in, const int* in_sizes, int n_in,
                              void* d_out, int out_size, void* d_ws, size_t ws_size,
                              hipStream_t stream)
{
    const float* qx   = (const float*)d_in[0];
    const float* kvx  = (const float*)d_in[1];
    const float* bias = (const float*)d_in[2];
    const float* Wq = (const float*)d_in[3];
    const float* Wk = (const float*)d_in[4];
    const float* Wv = (const float*)d_in[5];
    const float* Wg = (const float*)d_in[6];
    const float* bg = (const float*)d_in[7];
    const float* Wo = (const float*)d_in[8];
    const float* bo = (const float*)d_in[9];
    float* out = (float*)d_out;

    char* ws = (char*)d_ws;
    const size_t SZB = (size_t)B_ * N_ * CIN * 2;   // 2 MB per bf16 [4096][256]
    u16* Qw   = (u16*)(ws + 2 * SZB);
    u16* Kw   = (u16*)(ws + 3 * SZB);
    u16* Vt   = (u16*)(ws + 4 * SZB);
    u16* Gw   = (u16*)(ws + 5 * SZB);
    u16* Owg  = (u16*)(ws + 6 * SZB);
    const size_t WSZ = (size_t)CIN * CIN * 2;       // 128 KB per bf16 weight
    u16* WqT = (u16*)(ws + 7 * SZB + 0 * WSZ);
    u16* WkT = (u16*)(ws + 7 * SZB + 1 * WSZ);
    u16* WvT = (u16*)(ws + 7 * SZB + 2 * WSZ);
    u16* WgT = (u16*)(ws + 7 * SZB + 3 * WSZ);
    u16* WoT = (u16*)(ws + 7 * SZB + 4 * WSZ);

    prep80<<<dim3(80), 256, 0, stream>>>(Wq, Wk, Wv, Wg, Wo,
                                         WqT, WkT, WvT, WgT, WoT);
    proj_mfma<<<dim3(4, 64, 4), 256, 0, stream>>>(qx, kvx, WqT, WkT, WvT, WgT,
                                                  bg, Qw, Kw, Vt, Gw);
    attn_kernel<<<dim3(1024), 256, 0, stream>>>(Qw, Kw, Vt, bias, Gw, Owg);
    out_mfma<<<dim3(4, 64, 1), 256, 0, stream>>>(Owg, WoT, bo, out);
}

// Round 8
// 110.575 us; speedup vs baseline: 1.1166x; 1.1166x over previous
//
#include <hip/hip_runtime.h>
#include <hip/hip_bf16.h>

#define B_   2
#define N_   2048
#define CIN  256
#define NH   8
#define CH   32

typedef unsigned short u16;
typedef __attribute__((ext_vector_type(4))) float f32x4;
typedef __bf16 bf16x8 __attribute__((ext_vector_type(8)));
typedef u16 u16x4 __attribute__((ext_vector_type(4)));
typedef u16 u16x8 __attribute__((ext_vector_type(8)));

static __device__ __forceinline__ u16 b16(float f) {
    __bf16 h = (__bf16)f;
    union { __bf16 h; u16 u; } c; c.h = h; return c.u;
}
static __device__ __forceinline__ float bf2f(u16 u) {
    union { unsigned u; float f; } c; c.u = ((unsigned)u) << 16; return c.f;
}
static __device__ __forceinline__ float sigmoidf_(float x) {
    return 1.0f / (1.0f + __expf(-x));
}
// async global->LDS DMA, 16B per lane; LDS dest = wave-uniform base + lane*16
static __device__ __forceinline__ void gload_lds16(const void* g, void* lds) {
    __builtin_amdgcn_global_load_lds(
        (const __attribute__((address_space(1))) unsigned int*)g,
        (__attribute__((address_space(3))) unsigned int*)lds, 16, 0, 0);
}

// ---------------------------------------------------------------------------
// Best-of-all-rounds configuration (ledger r0-r7):
//  D1 prep80   : 80-block weight transpose+convert (r7, -launch vs 1104-blk)
//  D2 proj_mfma: staged 64x64 MFMA, X staged straight from f32 (r7; skips
//                the x->bf16 pre-pass entirely)
//  D3 attn     : r3 attn VERBATIM -- barrier-free, wave-private 3-buffer bias
//                DMA, counted vmcnt(2). Best measured attn; r6 key-split and
//                r7 register-ring both regressed (attn is bias-BW-bound).
//  D4 out_mfma : staged 64x64 MFMA output projection (r3).
// ---------------------------------------------------------------------------
#define LDW 136   // padded LDS row (u16): 272B; 272%128=16B -> conflict-free b128

static __device__ __forceinline__ u16x8 cvt8(float4 a, float4 b) {
    u16x8 o;
    o[0] = b16(a.x); o[1] = b16(a.y); o[2] = b16(a.z); o[3] = b16(a.w);
    o[4] = b16(b.x); o[5] = b16(b.y); o[6] = b16(b.z); o[7] = b16(b.w);
    return o;
}
static __device__ __forceinline__ void stg_b16(const u16* __restrict__ src, u16 (*dst)[LDW], int tid) {
#pragma unroll
    for (int i = 0; i < 4; i++) {
        const int e = tid + 256 * i, row = e >> 4, c = e & 15;
        *(bf16x8*)&dst[row][c * 8] = *(const bf16x8*)(src + (size_t)row * CIN + c * 8);
    }
}
static __device__ __forceinline__ void ld1_b16(const u16* __restrict__ src, bf16x8 r[4], int tid) {
#pragma unroll
    for (int i = 0; i < 4; i++) {
        const int e = tid + 256 * i, row = e >> 4, c = e & 15;
        r[i] = *(const bf16x8*)(src + (size_t)row * CIN + 128 + c * 8);
    }
}
static __device__ __forceinline__ void wr1_b16(const bf16x8 r[4], u16 (*dst)[LDW], int tid) {
#pragma unroll
    for (int i = 0; i < 4; i++) {
        const int e = tid + 256 * i, row = e >> 4, c = e & 15;
        *(bf16x8*)&dst[row][c * 8] = r[i];
    }
}
static __device__ __forceinline__ void stg_f32(const float* __restrict__ src, u16 (*dst)[LDW], int tid) {
#pragma unroll
    for (int i = 0; i < 4; i++) {
        const int e = tid + 256 * i, row = e >> 4, c = e & 15;
        const float* s = src + (size_t)row * CIN + c * 8;
        *(u16x8*)&dst[row][c * 8] = cvt8(*(const float4*)s, *(const float4*)(s + 4));
    }
}
static __device__ __forceinline__ void compute_phase(
    const u16 (*At)[LDW], const u16 (*Bt)[LDW], int w, int lr, int lq, f32x4 acc[4])
{
#pragma unroll
    for (int kk = 0; kk < 128; kk += 32) {
        bf16x8 af = *(const bf16x8*)&At[w * 16 + lr][kk + lq * 8];
#pragma unroll
        for (int nt = 0; nt < 4; nt++) {
            bf16x8 bf = *(const bf16x8*)&Bt[nt * 16 + lr][kk + lq * 8];
            acc[nt] = __builtin_amdgcn_mfma_f32_16x16x32_bf16(af, bf, acc[nt], 0, 0, 0);
        }
    }
}

// ---------------------------------------------------------------------------
// D1: 80 blocks -- transpose+convert weights -> Wt[n][k] bf16 (scale on Wq)
// ---------------------------------------------------------------------------
__global__ __launch_bounds__(256)
void prep80(const float* __restrict__ Wq, const float* __restrict__ Wk,
            const float* __restrict__ Wv, const float* __restrict__ Wg,
            const float* __restrict__ Wo,
            u16* __restrict__ WqT, u16* __restrict__ WkT,
            u16* __restrict__ WvT, u16* __restrict__ WgT,
            u16* __restrict__ WoT)
{
    const int wz = blockIdx.x;
    const int tid = threadIdx.x;
    const int z = wz >> 4, t16 = wz & 15;
    const int k0 = (t16 & 3) * 64, n0 = (t16 >> 2) * 64;
    const float* W = (z == 0) ? Wq : (z == 1) ? Wk : (z == 2) ? Wv : (z == 3) ? Wg : Wo;
    u16* Wt = (z == 0) ? WqT : (z == 1) ? WkT : (z == 2) ? WvT : (z == 3) ? WgT : WoT;
    const float s = (z == 0) ? 0.17677669529663687f : 1.0f;

    __shared__ float T[64][65];
    const int a = tid >> 4, c4 = (tid & 15) * 4;
#pragma unroll
    for (int i = 0; i < 4; i++) {
        float4 v = *(const float4*)&W[(size_t)(k0 + a + i * 16) * CIN + n0 + c4];
        T[a + i * 16][c4 + 0] = v.x * s; T[a + i * 16][c4 + 1] = v.y * s;
        T[a + i * 16][c4 + 2] = v.z * s; T[a + i * 16][c4 + 3] = v.w * s;
    }
    __syncthreads();
#pragma unroll
    for (int i = 0; i < 4; i++) {
        const int nr = a + i * 16;
        u16x4 o;
        o[0] = b16(T[c4 + 0][nr]); o[1] = b16(T[c4 + 1][nr]);
        o[2] = b16(T[c4 + 2][nr]); o[3] = b16(T[c4 + 3][nr]);
        *(u16x4*)&Wt[(size_t)(n0 + nr) * CIN + k0 + c4] = o;
    }
}

// ---------------------------------------------------------------------------
// D2: projections (z=0 Q, z=1 K, z=2 Vt, z=3 G); X staged from f32
// ---------------------------------------------------------------------------
__global__ __launch_bounds__(256, 4)
void proj_mfma(const float* __restrict__ qx, const float* __restrict__ kvx,
               const u16* __restrict__ WqT, const u16* __restrict__ WkT,
               const u16* __restrict__ WvT, const u16* __restrict__ WgT,
               const float* __restrict__ bgv,
               u16* __restrict__ Qw, u16* __restrict__ Kw,
               u16* __restrict__ Vt, u16* __restrict__ Gw)
{
    const int z = blockIdx.z;
    const int tid = threadIdx.x, w = tid >> 6, l = tid & 63, lr = l & 15, lq = l >> 4;

    __shared__ u16 At[64][LDW];
    __shared__ u16 Bt[64][LDW];

    f32x4 acc[4] = {{0,0,0,0},{0,0,0,0},{0,0,0,0},{0,0,0,0}};

    if (z != 2) {
        const float* Af = ((z == 1) ? kvx : qx) + (size_t)(blockIdx.y * 64) * CIN;
        const u16*   Bb = ((z == 0) ? WqT : (z == 1) ? WkT : WgT) + (size_t)(blockIdx.x * 64) * CIN;
        stg_f32(Af, At, tid);
        stg_b16(Bb, Bt, tid);
        __syncthreads();
        float4 raf[8]; bf16x8 rb[4];
#pragma unroll
        for (int i = 0; i < 4; i++) {
            const int e = tid + 256 * i, row = e >> 4, c = e & 15;
            const float* s = Af + (size_t)row * CIN + 128 + c * 8;
            raf[2 * i] = *(const float4*)s; raf[2 * i + 1] = *(const float4*)(s + 4);
        }
        ld1_b16(Bb, rb, tid);
        compute_phase(At, Bt, w, lr, lq, acc);
        __syncthreads();
#pragma unroll
        for (int i = 0; i < 4; i++) {
            const int e = tid + 256 * i, row = e >> 4, c = e & 15;
            *(u16x8*)&At[row][c * 8] = cvt8(raf[2 * i], raf[2 * i + 1]);
        }
        wr1_b16(rb, Bt, tid);
        __syncthreads();
        compute_phase(At, Bt, w, lr, lq, acc);

        const int m0 = blockIdx.y * 64 + w * 16, n0 = blockIdx.x * 64;
        if (z == 3) {
#pragma unroll
            for (int nt = 0; nt < 4; nt++) {
                const int col = n0 + nt * 16 + lr;
                const float bb = bgv[col];
#pragma unroll
                for (int r = 0; r < 4; r++)
                    Gw[(size_t)(m0 + lq * 4 + r) * CIN + col] = b16(sigmoidf_(acc[nt][r] + bb));
            }
        } else {
            u16* D = (z == 0) ? Qw : Kw;
#pragma unroll
            for (int nt = 0; nt < 4; nt++)
#pragma unroll
                for (int r = 0; r < 4; r++)
                    D[(size_t)(m0 + lq * 4 + r) * CIN + n0 + nt * 16 + lr] = b16(acc[nt][r]);
        }
    } else {
        const u16*   Ab = WvT + (size_t)(blockIdx.x * 64) * CIN;
        const float* Bf = kvx + (size_t)(blockIdx.y * 64) * CIN;
        stg_b16(Ab, At, tid);
        stg_f32(Bf, Bt, tid);
        __syncthreads();
        bf16x8 ra[4]; float4 rbf[8];
        ld1_b16(Ab, ra, tid);
#pragma unroll
        for (int i = 0; i < 4; i++) {
            const int e = tid + 256 * i, row = e >> 4, c = e & 15;
            const float* s = Bf + (size_t)row * CIN + 128 + c * 8;
            rbf[2 * i] = *(const float4*)s; rbf[2 * i + 1] = *(const float4*)(s + 4);
        }
        compute_phase(At, Bt, w, lr, lq, acc);
        __syncthreads();
        wr1_b16(ra, At, tid);
#pragma unroll
        for (int i = 0; i < 4; i++) {
            const int e = tid + 256 * i, row = e >> 4, c = e & 15;
            *(u16x8*)&Bt[row][c * 8] = cvt8(rbf[2 * i], rbf[2 * i + 1]);
        }
        __syncthreads();
        compute_phase(At, Bt, w, lr, lq, acc);

        const int c0 = blockIdx.x * 64 + w * 16;
        const int n0g = blockIdx.y * 64;
        const int bb_ = n0g >> 11, nl0 = n0g & (N_ - 1);
#pragma unroll
        for (int nt = 0; nt < 4; nt++)
#pragma unroll
            for (int r = 0; r < 4; r++)
                Vt[((size_t)bb_ * CIN + c0 + lq * 4 + r) * N_ + nl0 + nt * 16 + lr] = b16(acc[nt][r]);
    }
}

// ---------------------------------------------------------------------------
// D3: flash attention -- round-3 structure VERBATIM (best measured).
// Barrier-free: wave-private 3-buffer bias DMA, counted vmcnt(2), grid 512.
// ---------------------------------------------------------------------------
#define RMAX(x) { x = fmaxf(x, __shfl_xor(x, 1)); x = fmaxf(x, __shfl_xor(x, 2)); \
                  x = fmaxf(x, __shfl_xor(x, 4)); x = fmaxf(x, __shfl_xor(x, 8)); }
#define RSUM(x) { x += __shfl_xor(x, 1); x += __shfl_xor(x, 2); \
                  x += __shfl_xor(x, 4); x += __shfl_xor(x, 8); }

__global__ __launch_bounds__(256)
void attn_kernel(const u16* __restrict__ Qw, const u16* __restrict__ Kw,
                 const u16* __restrict__ Vt, const float* __restrict__ bias,
                 const u16* __restrict__ Gw, u16* __restrict__ Owg)
{
    const int bid = blockIdx.x;
    const int h = bid & 7, qt = (bid >> 3) & 31, b = bid >> 8;
    const int tid = threadIdx.x;
    const int w = tid >> 6, l = tid & 63, lr = l & 15, lq = l >> 4;
    const int qb = qt * 64;

    __shared__ __align__(16) float Btl[4][3][16][32];  // wave-private 3-buf bias
    __shared__ u16 Plds[4][8][4][16];                  // wave-private P staging

    const bf16x8 qf = *(const bf16x8*)(Qw + (size_t)(b * N_ + qb + w * 16 + lr) * CIN + h * CH + lq * 8);
    const u16* Kb = Kw + (size_t)(b * N_ + lr) * CIN + h * CH + lq * 8;
    const u16* Vb = Vt + (size_t)((b * NH + h) * CH + lr) * N_ + lq * 8;
    const float* biasW = bias + ((size_t)(b * NH + h) * N_ + qb + w * 16) * N_;

    const float* gl0 = biasW + (size_t)(l >> 3) * N_ + (l & 7) * 4;
    const float* gl1 = biasW + (size_t)(8 + (l >> 3)) * N_ + (l & 7) * 4;

#define STAGE(TT, BI) { \
    gload_lds16(gl0 + (size_t)(TT) * 32, &Btl[w][BI][0][0]); \
    gload_lds16(gl1 + (size_t)(TT) * 32, &Btl[w][BI][8][0]); }

#define KVLOAD(K) { kf0 = *(const bf16x8*)(Kb + (size_t)(K) * CIN); \
                    kf1 = *(const bf16x8*)(Kb + (size_t)((K) + 16) * CIN); \
                    vf0 = *(const bf16x8*)(Vb + (K)); \
                    vf1 = *(const bf16x8*)(Vb + 16 * N_ + (K)); }

    f32x4 acc0 = {0.f, 0.f, 0.f, 0.f}, acc1 = {0.f, 0.f, 0.f, 0.f};
    float m0v = 8.f, m1v = 8.f, m2v = 8.f, m3v = 8.f;   // defer-max init
    float l0 = 0.f, l1 = 0.f, l2 = 0.f, l3 = 0.f;
    bf16x8 kf0, kf1, vf0, vf1;

    STAGE(0, 0)
    __builtin_amdgcn_sched_barrier(0);
    KVLOAD(0)
    __builtin_amdgcn_sched_barrier(0);
    STAGE(1, 1)
    __builtin_amdgcn_sched_barrier(0);

    int cur = 0, nxt = 2;
    for (int t = 0; t < 64; t++) {
        // outstanding: [S(t):2][K(t):4][S(t+1):2] -> keep newest 2
        asm volatile("s_waitcnt vmcnt(2)" ::: "memory");
        const bf16x8 ck0 = kf0, ck1 = kf1, cv0 = vf0, cv1 = vf1;
        KVLOAD(((t + 1) & 63) * 32)
        __builtin_amdgcn_sched_barrier(0);
        STAGE((t + 2) & 63, nxt)
        __builtin_amdgcn_sched_barrier(0);

        const float* bt = &Btl[w][cur][lq * 4][0];
        f32x4 c0, c1;
        c0[0] = bt[0 * 32 + lr];      c0[1] = bt[1 * 32 + lr];
        c0[2] = bt[2 * 32 + lr];      c0[3] = bt[3 * 32 + lr];
        c1[0] = bt[0 * 32 + 16 + lr]; c1[1] = bt[1 * 32 + 16 + lr];
        c1[2] = bt[2 * 32 + 16 + lr]; c1[3] = bt[3 * 32 + 16 + lr];

        f32x4 s0 = __builtin_amdgcn_mfma_f32_16x16x32_bf16(qf, ck0, c0, 0, 0, 0);
        f32x4 s1 = __builtin_amdgcn_mfma_f32_16x16x32_bf16(qf, ck1, c1, 0, 0, 0);

        float pm0 = fmaxf(s0[0], s1[0]);
        float pm1 = fmaxf(s0[1], s1[1]);
        float pm2 = fmaxf(s0[2], s1[2]);
        float pm3 = fmaxf(s0[3], s1[3]);
        bool ev = (pm0 > m0v) || (pm1 > m1v) || (pm2 > m2v) || (pm3 > m3v);
        if (__any(ev)) {
            RMAX(pm0) RMAX(pm1) RMAX(pm2) RMAX(pm3)
            float t0 = fmaxf(m0v, pm0), t1 = fmaxf(m1v, pm1);
            float t2 = fmaxf(m2v, pm2), t3 = fmaxf(m3v, pm3);
            float sc0 = __expf(m0v - t0), sc1 = __expf(m1v - t1);
            float sc2 = __expf(m2v - t2), sc3 = __expf(m3v - t3);
            m0v = t0; m1v = t1; m2v = t2; m3v = t3;
            l0 *= sc0; l1 *= sc1; l2 *= sc2; l3 *= sc3;
            acc0[0] *= sc0; acc0[1] *= sc1; acc0[2] *= sc2; acc0[3] *= sc3;
            acc1[0] *= sc0; acc1[1] *= sc1; acc1[2] *= sc2; acc1[3] *= sc3;
        }
        float p00 = __expf(s0[0] - m0v), p01 = __expf(s0[1] - m1v);
        float p02 = __expf(s0[2] - m2v), p03 = __expf(s0[3] - m3v);
        float p10 = __expf(s1[0] - m0v), p11 = __expf(s1[1] - m1v);
        float p12 = __expf(s1[2] - m2v), p13 = __expf(s1[3] - m3v);
        l0 += p00 + p10; l1 += p01 + p11; l2 += p02 + p12; l3 += p03 + p13;

        u16* pw = &Plds[w][0][lq][lr];
        pw[0 * 64] = b16(p00); pw[1 * 64] = b16(p01);
        pw[2 * 64] = b16(p02); pw[3 * 64] = b16(p03);
        pw[4 * 64] = b16(p10); pw[5 * 64] = b16(p11);
        pw[6 * 64] = b16(p12); pw[7 * 64] = b16(p13);

        const bf16x8 pa = *(const bf16x8*)&Plds[w][(lq >> 1) * 4 + (lr & 3)][lr >> 2][(lq & 1) * 8];
        acc0 = __builtin_amdgcn_mfma_f32_16x16x32_bf16(pa, cv0, acc0, 0, 0, 0);
        acc1 = __builtin_amdgcn_mfma_f32_16x16x32_bf16(pa, cv1, acc1, 0, 0, 0);

        cur = (cur == 2) ? 0 : cur + 1;
        nxt = (nxt == 2) ? 0 : nxt + 1;
    }
#undef STAGE
#undef KVLOAD

    RSUM(l0) RSUM(l1) RSUM(l2) RSUM(l3)
    const float rr[4] = {1.0f / l0, 1.0f / l1, 1.0f / l2, 1.0f / l3};
    const f32x4 a0 = acc0, a1 = acc1;

    const u16* Gb = Gw + (size_t)(b * N_ + qb + w * 16 + lq * 4) * CIN + h * CH + lr;
    u16* Ob = Owg + (size_t)(b * N_ + qb + w * 16 + lq * 4) * CIN + h * CH + lr;
#pragma unroll
    for (int r = 0; r < 4; r++) {
        const float g0 = bf2f(Gb[r * CIN]), g1 = bf2f(Gb[r * CIN + 16]);
        Ob[r * CIN]      = b16(a0[r] * rr[r] * g0);
        Ob[r * CIN + 16] = b16(a1[r] * rr[r] * g1);
    }
}

// ---------------------------------------------------------------------------
// D4: out = Owg @ Wo + bo  (staged 64x64 core)
// ---------------------------------------------------------------------------
__global__ __launch_bounds__(256, 4)
void out_mfma(const u16* __restrict__ Owg, const u16* __restrict__ WoT,
              const float* __restrict__ bo, float* __restrict__ out)
{
    const int tid = threadIdx.x, w = tid >> 6, l = tid & 63, lr = l & 15, lq = l >> 4;
    const int m0 = blockIdx.y * 64 + w * 16, n0 = blockIdx.x * 64;

    __shared__ u16 At[64][LDW];
    __shared__ u16 Bt[64][LDW];

    const u16* Arows = Owg + (size_t)(blockIdx.y * 64) * CIN;
    const u16* Brows = WoT + (size_t)(blockIdx.x * 64) * CIN;

    f32x4 acc[4] = {{0,0,0,0},{0,0,0,0},{0,0,0,0},{0,0,0,0}};

    stg_b16(Arows, At, tid);
    stg_b16(Brows, Bt, tid);
    __syncthreads();
    bf16x8 ra[4], rb[4];
    ld1_b16(Arows, ra, tid);
    ld1_b16(Brows, rb, tid);
    compute_phase(At, Bt, w, lr, lq, acc);
    __syncthreads();
    wr1_b16(ra, At, tid);
    wr1_b16(rb, Bt, tid);
    __syncthreads();
    compute_phase(At, Bt, w, lr, lq, acc);

#pragma unroll
    for (int nt = 0; nt < 4; nt++) {
        const float bb = bo[n0 + nt * 16 + lr];
#pragma unroll
        for (int r = 0; r < 4; r++)
            out[(size_t)(m0 + lq * 4 + r) * CIN + n0 + nt * 16 + lr] = acc[nt][r] + bb;
    }
}

// ---------------------------------------------------------------------------
extern "C" void kernel_launch(void* const* d_in, const int* in_sizes, int n_in,
                              void* d_out, int out_size, void* d_ws, size_t ws_size,
                              hipStream_t stream)
{
    const float* qx   = (const float*)d_in[0];
    const float* kvx  = (const float*)d_in[1];
    const float* bias = (const float*)d_in[2];
    const float* Wq = (const float*)d_in[3];
    const float* Wk = (const float*)d_in[4];
    const float* Wv = (const float*)d_in[5];
    const float* Wg = (const float*)d_in[6];
    const float* bg = (const float*)d_in[7];
    const float* Wo = (const float*)d_in[8];
    const float* bo = (const float*)d_in[9];
    float* out = (float*)d_out;

    char* ws = (char*)d_ws;
    const size_t SZB = (size_t)B_ * N_ * CIN * 2;   // 2 MB per bf16 [4096][256]
    u16* Qw   = (u16*)(ws + 2 * SZB);
    u16* Kw   = (u16*)(ws + 3 * SZB);
    u16* Vt   = (u16*)(ws + 4 * SZB);
    u16* Gw   = (u16*)(ws + 5 * SZB);
    u16* Owg  = (u16*)(ws + 6 * SZB);
    const size_t WSZ = (size_t)CIN * CIN * 2;       // 128 KB per bf16 weight
    u16* WqT = (u16*)(ws + 7 * SZB + 0 * WSZ);
    u16* WkT = (u16*)(ws + 7 * SZB + 1 * WSZ);
    u16* WvT = (u16*)(ws + 7 * SZB + 2 * WSZ);
    u16* WgT = (u16*)(ws + 7 * SZB + 3 * WSZ);
    u16* WoT = (u16*)(ws + 7 * SZB + 4 * WSZ);

    prep80<<<dim3(80), 256, 0, stream>>>(Wq, Wk, Wv, Wg, Wo,
                                         WqT, WkT, WvT, WgT, WoT);
    proj_mfma<<<dim3(4, 64, 4), 256, 0, stream>>>(qx, kvx, WqT, WkT, WvT, WgT,
                                                  bg, Qw, Kw, Vt, Gw);
    attn_kernel<<<dim3(512), 256, 0, stream>>>(Qw, Kw, Vt, bias, Gw, Owg);
    out_mfma<<<dim3(4, 64, 1), 256, 0, stream>>>(Owg, WoT, bo, out);
}